// Round 30
// baseline (186.137 us; speedup 1.0000x reference)
//
#include <hip/hip_runtime.h>
#include <hip/hip_fp16.h>
#include <math.h>

#define SLOPE 0.2f
#define LOG2E 1.4426950408889634f

typedef _Float16 half8_t __attribute__((ext_vector_type(8)));
typedef _Float16 half2_t __attribute__((ext_vector_type(2)));
typedef float    f32x4_t __attribute__((ext_vector_type(4)));

__device__ __forceinline__ unsigned short pk_f16(float x) {
    return __half_as_ushort(__float2half(x));
}
__device__ __forceinline__ half2_t u2h2(unsigned int u) {
    union { unsigned int u; half2_t h; } c; c.u = u; return c.h;
}

// ---------- interleaved MFMA-gemm ∥ XCD-private histogram ----------------
// blockIdx%3==2 -> histogram block g=blockIdx/3: 2 edges/thread (512/block)
// into cnt8[g&7]; rank(ushort)=atomic return. Else gemm block
// gemmIdx=(blockIdx/3)*2+blockIdx%3: 16 nodes x 64 ch; wave w = 16x16
// D-tile at ch0=16w via 4x mfma_f32_16x16x32_f16 (K=128); W cvt in-reg.
// C/D: node = n0 + (lane>>4)*4 + r, ch = ch0 + (lane&15)   [m89 layout]
__global__ __launch_bounds__(256, 8) void gemm_hist_kernel(const float* __restrict__ h,
                                                           const float* __restrict__ W,
                                                           unsigned short* __restrict__ zh,
                                                           const int* __restrict__ dst,
                                                           int* __restrict__ cnt8,
                                                           unsigned short* __restrict__ rank,
                                                           int n, int ne) {
    int r3 = blockIdx.x % 3;
    int g3 = blockIdx.x / 3;
    if (r3 == 2) {
        // ---- histogram block ----
        int* __restrict__ cnt = cnt8 + (size_t)(g3 & 7) * n;
        int i = g3 * 256 + threadIdx.x;
        int base = i * 2;
        if (base + 1 < ne) {
            int2 d = *(const int2*)(dst + base);
            unsigned int r0 = atomicAdd(&cnt[d.x], 1);
            unsigned int r1 = atomicAdd(&cnt[d.y], 1);
            *(unsigned int*)(rank + base) = (r1 << 16) | (r0 & 0xFFFF);
        } else if (base < ne) {
            rank[base] = (unsigned short)atomicAdd(&cnt[dst[base]], 1);
        }
        return;
    }

    // ---- gemm block (MFMA) ----
    int gemmIdx = g3 * 2 + r3;
    int n0 = gemmIdx * 16;
    if (n0 >= n) return;
    int lane = threadIdx.x & 63;
    int wave = threadIdx.x >> 6;
    int row = lane & 15;          // A row (node) and B col (channel)
    int grp = lane >> 4;          // k-group
    int ch0 = wave * 16;

    const float* __restrict__ hp = h + (size_t)(n0 + row) * 128 + grp * 8;
    const float* __restrict__ wp = W + (size_t)(ch0 + row) * 128 + grp * 8;

    f32x4_t acc = {0.f, 0.f, 0.f, 0.f};
#pragma unroll
    for (int c = 0; c < 4; c++) {
        int kc = c * 32;
        float4 a0 = *(const float4*)(hp + kc);
        float4 a1 = *(const float4*)(hp + kc + 4);
        half8_t av;
        av[0] = (_Float16)a0.x; av[1] = (_Float16)a0.y;
        av[2] = (_Float16)a0.z; av[3] = (_Float16)a0.w;
        av[4] = (_Float16)a1.x; av[5] = (_Float16)a1.y;
        av[6] = (_Float16)a1.z; av[7] = (_Float16)a1.w;
        float4 b0 = *(const float4*)(wp + kc);
        float4 b1 = *(const float4*)(wp + kc + 4);
        half8_t bv;
        bv[0] = (_Float16)b0.x; bv[1] = (_Float16)b0.y;
        bv[2] = (_Float16)b0.z; bv[3] = (_Float16)b0.w;
        bv[4] = (_Float16)b1.x; bv[5] = (_Float16)b1.y;
        bv[6] = (_Float16)b1.z; bv[7] = (_Float16)b1.w;
        acc = __builtin_amdgcn_mfma_f32_16x16x32_f16(av, bv, acc, 0, 0, 0);
    }
#pragma unroll
    for (int r = 0; r < 4; r++)
        zh[(size_t)(n0 + grp * 4 + r) * 64 + ch0 + row] = pk_f16(acc[r]);
}

// -------------------- scan over 8-copy histogram (4096/block) ------------
__global__ __launch_bounds__(256) void scan1(const int* __restrict__ cnt8,
                                             int* __restrict__ starts,
                                             int* __restrict__ bsums, int n) {
    __shared__ int ls[256];
    int tbase = blockIdx.x * 4096 + threadIdx.x * 16;
    int tot[16];
#pragma unroll
    for (int k = 0; k < 16; k++) tot[k] = 0;
    if (tbase + 15 < n) {
#pragma unroll
        for (int c = 0; c < 8; c++) {
            const int* cp = cnt8 + (size_t)c * n + tbase;
#pragma unroll
            for (int q = 0; q < 4; q++) {
                int4 v = *(const int4*)(cp + q * 4);
                tot[q * 4 + 0] += v.x; tot[q * 4 + 1] += v.y;
                tot[q * 4 + 2] += v.z; tot[q * 4 + 3] += v.w;
            }
        }
    } else {
        for (int k = 0; k < 16; k++) {
            int idx = tbase + k;
            if (idx < n)
                for (int c = 0; c < 8; c++) tot[k] += cnt8[(size_t)c * n + idx];
        }
    }
    int s = 0;
#pragma unroll
    for (int k = 0; k < 16; k++) s += tot[k];
    ls[threadIdx.x] = s;
    __syncthreads();
    for (int off = 1; off < 256; off <<= 1) {
        int t = threadIdx.x >= off ? ls[threadIdx.x - off] : 0;
        __syncthreads();
        ls[threadIdx.x] += t;
        __syncthreads();
    }
    int run = ls[threadIdx.x] - s;
    if (threadIdx.x == 255) bsums[blockIdx.x] = ls[255];
#pragma unroll
    for (int k = 0; k < 16; k++) {
        int idx = tbase + k;
        if (idx < n) starts[idx] = run;
        run += tot[k];
    }
}

// scan3: add cross-block prefix, set starts[n], convert cnt8 in place to
// per-copy scatter bases.
__global__ __launch_bounds__(256) void scan3(int* __restrict__ starts,
                                             const int* __restrict__ bsums,
                                             int* __restrict__ cnt8,
                                             int n, int ne) {
    __shared__ int base_s;
    int i = blockIdx.x * 256 + threadIdx.x;
    if (threadIdx.x == 0) {
        int reg = (int)(blockIdx.x >> 4);          // 4096-region = 16 blocks
        int s = 0;
        for (int b = 0; b < reg; b++) s += bsums[b];
        base_s = s;
        if (blockIdx.x == 0) starts[n] = ne;
    }
    __syncthreads();
    if (i >= n) return;
    int b = starts[i] + base_s;
    starts[i] = b;
#pragma unroll
    for (int c = 0; c < 8; c++) {
        size_t off = (size_t)c * n + i;
        int t = cnt8[off];
        cnt8[off] = b;
        b += t;
    }
}

// ------ scatter src into CSR (rank + per-copy base, 16 edges/thread) -----
// copy of edge e = (e>>9)&7 (hist blocks own 512-edge chunks). 16-aligned
// groups never straddle a chunk boundary. 16 independent store chains.
__global__ __launch_bounds__(256) void scatter16_kernel(const int* __restrict__ src,
                                                        const int* __restrict__ dst,
                                                        const int* __restrict__ cnt8,
                                                        const unsigned short* __restrict__ rank,
                                                        int* __restrict__ csr_src,
                                                        int n, int ne) {
    int i = blockIdx.x * 256 + threadIdx.x;
    int base = i * 16;
    if (base + 15 < ne) {
        const int* __restrict__ cb = cnt8 + (size_t)((base >> 9) & 7) * n;
        int4 s[4], d[4];
        uint4 rp0 = *(const uint4*)(rank + base);       // edges 0..7
        uint4 rp1 = *(const uint4*)(rank + base + 8);   // edges 8..15
#pragma unroll
        for (int q = 0; q < 4; q++) {
            s[q] = *(const int4*)(src + base + q * 4);
            d[q] = *(const int4*)(dst + base + q * 4);
        }
        unsigned int rr[8] = {rp0.x, rp0.y, rp0.z, rp0.w, rp1.x, rp1.y, rp1.z, rp1.w};
#pragma unroll
        for (int q = 0; q < 4; q++) {
            csr_src[cb[d[q].x] + (rr[q * 2] & 0xFFFF)]     = s[q].x;
            csr_src[cb[d[q].y] + (rr[q * 2] >> 16)]        = s[q].y;
            csr_src[cb[d[q].z] + (rr[q * 2 + 1] & 0xFFFF)] = s[q].z;
            csr_src[cb[d[q].w] + (rr[q * 2 + 1] >> 16)]    = s[q].w;
        }
    } else {
        for (int e = base; e < ne; e++) {
            const int* cb = cnt8 + (size_t)((e >> 9) & 7) * n;
            csr_src[cb[dst[e]] + rank[e]] = src[e];
        }
    }
}

// ---------- fused: MFMA dot + online softmax + aggregation + elu ---------
// One wave per node. Per 16-edge chunk: A-frag = 16 gathered z_src rows
// (lane: row=lane&15, k-octet=lane>>4), B-frag = z_dst broadcast over cols
// (D cols replicate => lane holds its group's 4 edge-dots in acc[0..3]).
__global__ __launch_bounds__(256) void fused_node(const unsigned short* __restrict__ zh,
                                                  const int* __restrict__ starts,
                                                  const int* __restrict__ csr_src,
                                                  float4* __restrict__ out4, int n) {
    int node = blockIdx.x * 4 + (threadIdx.x >> 6);
    if (node >= n) return;
    int lane = threadIdx.x & 63;
    int g4 = lane >> 4;       // k-octet for MFMA; edge-quad owner for agg
    int q4 = lane & 15;       // A edge-row for MFMA gather; ch-quad for agg
    int rs = starts[node], re = starts[node + 1];

    const unsigned short* __restrict__ zdp = zh + (size_t)node * 64 + g4 * 8;
    half8_t bv0 = *(const half8_t*)(zdp);        // zd[k= 0..31], this octet
    half8_t bv1 = *(const half8_t*)(zdp + 32);   // zd[k=32..63], this octet

    float m = -1e30f, denom = 0.f;
    float4 out = make_float4(0.f, 0.f, 0.f, 0.f);

    for (int c = rs; c < re; c += 64) {
        int j = c + lane;
        int sv = j < re ? csr_src[j] : 0;
        int cn = min(64, re - c);
        for (int t = 0; t * 16 < cn; t++) {
            // ---- dot via MFMA: 16 edges, K=64 in 2 chunks ----
            int eidx = t * 16 + q4;
            int se = __shfl(sv, eidx < cn ? eidx : 0);
            const unsigned short* ap = zh + (size_t)se * 64 + g4 * 8;
            half8_t a0 = *(const half8_t*)(ap);
            half8_t a1 = *(const half8_t*)(ap + 32);
            f32x4_t acc = {0.f, 0.f, 0.f, 0.f};
            acc = __builtin_amdgcn_mfma_f32_16x16x32_f16(a0, bv0, acc, 0, 0, 0);
            acc = __builtin_amdgcn_mfma_f32_16x16x32_f16(a1, bv1, acc, 0, 0, 0);
            // lane's 4 edges: e = t*16 + g4*4 + jj   [m89 D row mapping]
            float e2[4];
            float cmax = -2e30f;
#pragma unroll
            for (int jj = 0; jj < 4; jj++) {
                float p = acc[jj];
                float e = fmaxf(p, SLOPE * p) * LOG2E;   // leaky, exp2 domain
                bool v = (t * 16 + g4 * 4 + jj) < cn;
                e2[jj] = v ? e : -2e30f;
                cmax = fmaxf(cmax, e2[jj]);
            }
            cmax = fmaxf(cmax, __shfl_xor(cmax, 16));
            cmax = fmaxf(cmax, __shfl_xor(cmax, 32));   // wave-uniform chunk max
            if (cmax > m) {                              // uniform branch
                float sc = exp2f(m - cmax);              // 0 on first chunk
                denom *= sc;
                out.x *= sc; out.y *= sc; out.z *= sc; out.w *= sc;
                m = cmax;
            }
            float ex[4];
#pragma unroll
            for (int jj = 0; jj < 4; jj++) {
                ex[jj] = exp2f(e2[jj] - m);              // 0 for invalid slots
                denom += ex[jj];
            }
            // ---- aggregation: lane owns ch-quad q4 of its group's edges ----
#pragma unroll
            for (int jj = 0; jj < 4; jj++) {
                int ei = t * 16 + g4 * 4 + jj;
                int sa = __shfl(sv, ei < cn ? ei : 0);   // ex=0 kills invalid
                uint2 w = *(const uint2*)(zh + (size_t)sa * 64 + q4 * 4);
                half2_t lo = u2h2(w.x), hi = u2h2(w.y);
                out.x = fmaf(ex[jj], (float)lo[0], out.x);
                out.y = fmaf(ex[jj], (float)lo[1], out.y);
                out.z = fmaf(ex[jj], (float)hi[0], out.z);
                out.w = fmaf(ex[jj], (float)hi[1], out.w);
            }
        }
    }
    // merge the 4 k-groups (lane = g4*16+q4: masks 16,32 flip g4 only)
#pragma unroll
    for (int msk = 16; msk < 64; msk <<= 1) {
        denom += __shfl_xor(denom, msk);
        out.x += __shfl_xor(out.x, msk);
        out.y += __shfl_xor(out.y, msk);
        out.z += __shfl_xor(out.z, msk);
        out.w += __shfl_xor(out.w, msk);
    }
    if (g4 == 0) {
        float inv = denom > 0.f ? 1.f / denom : 0.f;
        float4 r;
        float x;
        x = out.x * inv; r.x = x > 0.f ? x : exp2f(x * LOG2E) - 1.f;
        x = out.y * inv; r.y = x > 0.f ? x : exp2f(x * LOG2E) - 1.f;
        x = out.z * inv; r.z = x > 0.f ? x : exp2f(x * LOG2E) - 1.f;
        x = out.w * inv; r.w = x > 0.f ? x : exp2f(x * LOG2E) - 1.f;
        out4[(size_t)node * 16 + q4] = r;                // coalesced 256B/node
    }
}

// -------------------------------------------------------------- launch ----
extern "C" void kernel_launch(void* const* d_in, const int* in_sizes, int n_in,
                              void* d_out, int out_size, void* d_ws, size_t ws_size,
                              hipStream_t stream) {
    const float* h   = (const float*)d_in[0];
    const float* W   = (const float*)d_in[1];
    const int*   src = (const int*)d_in[2];
    const int*   dst = (const int*)d_in[3];
    int n  = in_sizes[0] / 128;   // 100000
    int ne = in_sizes[2];         // 1600000

    // 16B-aligned layout (~26 MB): zh | rank | cnt8 | csr_src | starts
    unsigned short* zh      = (unsigned short*)d_ws;             // 12.8 MB
    unsigned short* rank    = zh + (size_t)n * 64;               // 3.2 MB
    int*            cnt8    = (int*)(rank + ne);                 // 3.2 MB
    int*            csr_src = cnt8 + (size_t)8 * n;              // 6.4 MB
    int*            starts  = csr_src + ne;                      // n+1
    int*            bsums   = starts + ((n + 5) & ~3);           // 32

    int nbHist = (ne / 2 + 255) / 256;                // 3125
    int nbTotal = (nbHist + 1) * 3;                   // 9378 (gemm = 6252)
    int nb_scan = (n + 4095) / 4096;                  // 25

    hipMemsetAsync(cnt8, 0, (size_t)8 * n * sizeof(int), stream);
    gemm_hist_kernel<<<nbTotal, 256, 0, stream>>>(h, W, zh, dst, cnt8, rank, n, ne);
    scan1<<<nb_scan, 256, 0, stream>>>(cnt8, starts, bsums, n);
    scan3<<<(n + 255) / 256, 256, 0, stream>>>(starts, bsums, cnt8, n, ne);
    scatter16_kernel<<<(ne / 16 + 255) / 256, 256, 0, stream>>>(src, dst, cnt8,
                                                                rank, csr_src, n, ne);
    fused_node<<<(n + 3) / 4, 256, 0, stream>>>(zh, starts, csr_src,
                                                (float4*)d_out, n);
}